// Round 6
// baseline (378.436 us; speedup 1.0000x reference)
//
#include <hip/hip_runtime.h>
#include <hip/hip_bf16.h>

// ---------------------------------------------------------------------------
// TinyMNISTNet: out = relu(x @ Wq1^T + b1) @ Wq2^T + b2, ternarized weights.
// x: [65536,784] fp32; W1: [64,784]; b1:[64]; W2:[10,64]; b2:[10]; out fp32 [65536,10].
//
// R6: fix the K-loop's hidden vmcnt(0) serialization. Previous rounds loaded
// the 4 B-fragments in the SAME iteration as the MFMAs consuming them; being
// the newest outstanding loads, waiting for them drained the HBM x-prefetch
// too -> iteration period ~ full HBM latency. Now B is software-pipelined one
// step ahead (bcur/bnxt), so MFMA waits leave ~6 loads (x-prefetch + B-next)
// in flight every iteration. Rolled loop pinned with unroll(disable).
// ---------------------------------------------------------------------------

typedef __attribute__((ext_vector_type(4))) float f32x4;
typedef __attribute__((ext_vector_type(8))) short s16x8;
typedef __attribute__((ext_vector_type(4))) short s16x4;

#define K1 784
#define K1_PAD 800          // 25 K-steps of 32
#define NHID 64
#define NOUT 10

// lgkmcnt(0), vmcnt=63, expcnt=7  (gfx9 encoding)
#define WAIT_LGKM0() __builtin_amdgcn_s_waitcnt(0xC07F)

// packed f32x2 -> bf16x2 (RNE); inputs finite
static __device__ __forceinline__ unsigned int cvt_pk_bf16(float a, float b) {
    float2 f; f.x = a; f.y = b;
    __hip_bfloat162 h = __float22bfloat162_rn(f);
    unsigned int u;
    __builtin_memcpy(&u, &h, 4);      // .x low 16, .y high 16
    return u;
}

// scalar RNE f32->bf16 bits (epilogue only)
static __device__ __forceinline__ unsigned short f2bf_rne(float f) {
    unsigned int u = __builtin_bit_cast(unsigned int, f);
    unsigned int r = u + 0x7FFFu + ((u >> 16) & 1u);
    return (unsigned short)(r >> 16);
}

// block-wide f64 sum for 256-thread blocks (4 waves); all threads get result
static __device__ double block_sum256(double v, double* red) {
    #pragma unroll
    for (int off = 32; off > 0; off >>= 1) v += __shfl_down(v, off, 64);
    const int w = threadIdx.x >> 6;
    const int lane = threadIdx.x & 63;
    __syncthreads();                 // protect red[] reuse across calls
    if (lane == 0) red[w] = v;
    __syncthreads();
    return red[0] + red[1] + red[2] + red[3];
}

// ---------------------------------------------------------------------------
// parts (doubles): [0..63] sm1 partials, [64..127] cn1 partials, [128] alpha2
// Grid: 64 blocks x 256. Each block: redundant full sum|W1| (identical delta1
// in every block), quantize W1 row b, write (sm,cn) partial. Block 0 also
// does W2 end-to-end and stores alpha2.
// ---------------------------------------------------------------------------
__global__ __launch_bounds__(256) void tern_kernel(
    const float* __restrict__ W1, const float* __restrict__ W2,
    unsigned short* __restrict__ W1q, unsigned short* __restrict__ W2q,
    double* __restrict__ parts)
{
    __shared__ double red[4];
    const int tid = threadIdx.x;

    double s = 0.0;
    for (int i = tid; i < NHID * K1; i += 256) s += (double)fabsf(W1[i]);
    s = block_sum256(s, red);
    const float delta1 = (float)(0.7 * (s / (double)(NHID * K1)));

    const int n = blockIdx.x;
    double sm = 0.0, cn = 0.0;
    for (int k = tid; k < K1_PAD; k += 256) {
        unsigned short v = 0;
        if (k < K1) {
            float w = W1[n * K1 + k];
            float a = fabsf(w);
            if (a > delta1) { v = (w > 0.0f) ? 0x3F80u : 0xBF80u; sm += (double)a; cn += 1.0; }
        }
        W1q[n * K1_PAD + k] = v;
    }
    sm = block_sum256(sm, red);
    cn = block_sum256(cn, red);
    if (tid == 0) { parts[n] = sm; parts[64 + n] = cn; }

    if (blockIdx.x == 0) {
        double s2 = 0.0;
        for (int i = tid; i < NOUT * NHID; i += 256) s2 += (double)fabsf(W2[i]);
        s2 = block_sum256(s2, red);
        const float delta2 = (float)(0.7 * (s2 / (double)(NOUT * NHID)));
        double sm2 = 0.0, cn2 = 0.0;
        for (int i = tid; i < 16 * NHID; i += 256) {
            int r = i >> 6, k = i & 63;
            unsigned short v = 0;
            if (r < NOUT) {
                float w = W2[r * NHID + k];
                float a = fabsf(w);
                if (a > delta2) { v = (w > 0.0f) ? 0x3F80u : 0xBF80u; sm2 += (double)a; cn2 += 1.0; }
            }
            W2q[i] = v;
        }
        sm2 = block_sum256(sm2, red);
        cn2 = block_sum256(cn2, red);
        if (tid == 0) parts[128] = sm2 / fmax(cn2, 1.0);
    }
}

// ---------------------------------------------------------------------------
// Fused 2-layer kernel. 256 threads = 4 waves; each wave: 16 batch rows x all
// 64 hidden features, then 16x10 outputs. Grid: nrows/64 = 1024 (4 blocks/CU,
// all resident).
//
// K-loop (rolled, pinned): per iteration issue x-prefetch (chunk ks+1, HBM)
// and B-prefetch (chunk ks+1, L2) FIRST; then convert + wave-private LDS
// round-trip for chunk ks's A-fragments; then 4 MFMA consuming bcur (loaded
// LAST iteration) -> waits leave this iteration's 6 loads in flight.
// Tail chunk 24 handled branchlessly (clamped in-row reload x zero weights).
//
// MFMA 16x16x32 bf16 layouts (m89/m91/m120-verified):
//   A[m=lane&15][k=quad*8+j], B[n=lane&15][k=quad*8+j], C/D: col=lane&15, row=quad*4+reg
// ---------------------------------------------------------------------------
__global__ __launch_bounds__(256) void fused_kernel(
    const float* __restrict__ x,
    const float* __restrict__ b1,
    const float* __restrict__ b2,
    const short* __restrict__ W1q,   // [64][800] bf16 signs
    const short* __restrict__ W2q,   // [16][64]  bf16 signs
    const double* __restrict__ parts,
    float* __restrict__ out)
{
    const int tid  = threadIdx.x;
    const int wave = tid >> 6;
    const int lane = tid & 63;
    const int low  = lane & 15;
    const int quad = lane >> 4;
    const int m0 = blockIdx.x * 64 + wave * 16;

    // staging-load role: 8 lanes per row, 16B per lane (contiguous 128B/row)
    const int srow = lane >> 3;      // 0..7
    const int scol = lane & 7;       // *16B
    const float* g0 = x + (size_t)(m0 + srow) * K1 + scol * 4;
    const float* g1 = g0 + 8 * K1;
    // tail chunk 24 base: float 768 + clamped in-row column (k>=784 weights are 0)
    const float* g0t = x + (size_t)(m0 + srow) * K1 + 768 + (scol & 3) * 4;
    const float* g1t = g0t + 8 * K1;

    const short* wb0 = W1q + (size_t)(low     ) * K1_PAD + quad * 8;
    const short* wb1 = W1q + (size_t)(low + 16) * K1_PAD + quad * 8;
    const short* wb2 = W1q + (size_t)(low + 32) * K1_PAD + quad * 8;
    const short* wb3 = W1q + (size_t)(low + 48) * K1_PAD + quad * 8;

    __shared__ __align__(16) unsigned short stage[4][2][16][32];  // wave-private dbuf
    __shared__ __align__(16) unsigned short h_lds[4][16][72];     // layer-2 A staging

    f32x4 acc[4];
    #pragma unroll
    for (int nt = 0; nt < 4; ++nt) acc[nt] = (f32x4){0.f, 0.f, 0.f, 0.f};

    // prologue: chunk-0 x and chunk-0 B in flight
    f32x4 c0 = *(const f32x4*)(g0);
    f32x4 c1 = *(const f32x4*)(g1);
    s16x8 bcur0 = *(const s16x8*)(wb0);
    s16x8 bcur1 = *(const s16x8*)(wb1);
    s16x8 bcur2 = *(const s16x8*)(wb2);
    s16x8 bcur3 = *(const s16x8*)(wb3);

    int buf = 0;
    #pragma clang loop unroll(disable)
    for (int ks = 0; ks < 25; ++ks) {
        // ---- prefetch chunk ks+1: x first (HBM), then B (L2) ----
        f32x4 n0 = c0, n1 = c1;
        s16x8 bnxt0 = bcur0, bnxt1 = bcur1, bnxt2 = bcur2, bnxt3 = bcur3;
        if (ks < 24) {
            const float* p0 = (ks == 23) ? g0t : (g0 + (ks + 1) * 32);
            const float* p1 = (ks == 23) ? g1t : (g1 + (ks + 1) * 32);
            n0 = *(const f32x4*)(p0);
            n1 = *(const f32x4*)(p1);
            bnxt0 = *(const s16x8*)(wb0 + (ks + 1) * 32);
            bnxt1 = *(const s16x8*)(wb1 + (ks + 1) * 32);
            bnxt2 = *(const s16x8*)(wb2 + (ks + 1) * 32);
            bnxt3 = *(const s16x8*)(wb3 + (ks + 1) * 32);
        }

        // ---- convert chunk ks -> bf16, stash to wave-private LDS ----
        unsigned int pk[4];
        pk[0] = cvt_pk_bf16(c0[0], c0[1]); pk[1] = cvt_pk_bf16(c0[2], c0[3]);
        pk[2] = cvt_pk_bf16(c1[0], c1[1]); pk[3] = cvt_pk_bf16(c1[2], c1[3]);
        s16x4 p0v, p1v;
        __builtin_memcpy(&p0v, &pk[0], 8);
        __builtin_memcpy(&p1v, &pk[2], 8);
        *(s16x4*)&stage[wave][buf][srow][scol * 4]     = p0v;
        *(s16x4*)&stage[wave][buf][8 + srow][scol * 4] = p1v;

        WAIT_LGKM0();   // wave-private LDS write -> cross-lane read (DS drain only)

        s16x8 a = *(const s16x8*)&stage[wave][buf][low][quad * 8];
        // MFMAs consume bcur (loaded LAST iteration) -> this iter's 6 loads stay in flight
        acc[0] = __builtin_amdgcn_mfma_f32_16x16x32_bf16(a, bcur0, acc[0], 0, 0, 0);
        acc[1] = __builtin_amdgcn_mfma_f32_16x16x32_bf16(a, bcur1, acc[1], 0, 0, 0);
        acc[2] = __builtin_amdgcn_mfma_f32_16x16x32_bf16(a, bcur2, acc[2], 0, 0, 0);
        acc[3] = __builtin_amdgcn_mfma_f32_16x16x32_bf16(a, bcur3, acc[3], 0, 0, 0);

        c0 = n0; c1 = n1;
        bcur0 = bnxt0; bcur1 = bnxt1; bcur2 = bnxt2; bcur3 = bnxt3;
        buf ^= 1;
    }

    // ---- alpha1 from 64 f64 partials via shuffle butterfly; alpha2 direct ----
    double smd = parts[lane];
    double cnd = parts[64 + lane];
    #pragma unroll
    for (int off = 32; off > 0; off >>= 1) {
        smd += __shfl_down(smd, off, 64);
        cnd += __shfl_down(cnd, off, 64);
    }
    smd = __shfl(smd, 0, 64);
    cnd = __shfl(cnd, 0, 64);
    const float alpha1 = (float)(smd / fmax(cnd, 1.0));
    const float alpha2 = (float)parts[128];

    // ---- epilogue 1: alpha1*acc + b1, relu, bf16 -> LDS (C-layout -> A-layout) ----
    #pragma unroll
    for (int nt = 0; nt < 4; ++nt) {
        const int n = nt * 16 + low;
        const float bias = b1[n];
        #pragma unroll
        for (int r = 0; r < 4; ++r) {
            float hv = fmaxf(0.0f, fmaf(alpha1, acc[nt][r], bias));
            h_lds[wave][quad * 4 + r][n] = f2bf_rne(hv);
        }
    }
    WAIT_LGKM0();

    // ---- layer 2: [16x64] x [64x16] via 2 MFMA steps ----
    s16x8 a0 = *(const s16x8*)(&h_lds[wave][low][quad * 8]);
    s16x8 a1 = *(const s16x8*)(&h_lds[wave][low][32 + quad * 8]);
    s16x8 w0 = *(const s16x8*)(W2q + low * 64 + quad * 8);
    s16x8 w1 = *(const s16x8*)(W2q + low * 64 + 32 + quad * 8);

    f32x4 acc2 = (f32x4){0.f, 0.f, 0.f, 0.f};
    acc2 = __builtin_amdgcn_mfma_f32_16x16x32_bf16(a0, w0, acc2, 0, 0, 0);
    acc2 = __builtin_amdgcn_mfma_f32_16x16x32_bf16(a1, w1, acc2, 0, 0, 0);

    // ---- epilogue 2: alpha2*acc2 + b2, store fp32 ----
    if (low < NOUT) {
        const float bias2 = b2[low];
        #pragma unroll
        for (int r = 0; r < 4; ++r) {
            const int row = m0 + quad * 4 + r;
            out[(size_t)row * NOUT + low] = fmaf(alpha2, acc2[r], bias2);
        }
    }
}

// ---------------------------------------------------------------------------
extern "C" void kernel_launch(void* const* d_in, const int* in_sizes, int n_in,
                              void* d_out, int out_size, void* d_ws, size_t ws_size,
                              hipStream_t stream) {
    const float* x  = (const float*)d_in[0];
    const float* W1 = (const float*)d_in[1];
    const float* b1 = (const float*)d_in[2];
    const float* W2 = (const float*)d_in[3];
    const float* b2 = (const float*)d_in[4];
    float* out = (float*)d_out;

    const int nrows = in_sizes[0] / K1;   // 65536

    // ws layout: parts 129 doubles (pad to 2KB) | W1q [64*800] bf16 | W2q [16*64] bf16
    double* parts = (double*)d_ws;
    unsigned short* W1q = (unsigned short*)((char*)d_ws + 2048);
    unsigned short* W2q = W1q + NHID * K1_PAD;

    tern_kernel<<<64, 256, 0, stream>>>(W1, W2, W1q, W2q, parts);

    const int nblocks = nrows / 64;       // 64 rows per block (16 per wave)
    fused_kernel<<<nblocks, 256, 0, stream>>>(x, b1, b2, (const short*)W1q,
                                              (const short*)W2q, parts, out);
}

// Round 7
// 308.747 us; speedup vs baseline: 1.2257x; 1.2257x over previous
//
#include <hip/hip_runtime.h>
#include <hip/hip_bf16.h>

// ---------------------------------------------------------------------------
// TinyMNISTNet: out = relu(x @ Wq1^T + b1) @ Wq2^T + b2, ternarized weights.
// x: [65536,784] fp32; W1: [64,784]; b1:[64]; W2:[10,64]; b2:[10]; out fp32 [65536,10].
//
// R7: VERBATIM resubmission of the R2 source (the only config that measured
// 306 us; R3/R5/R6 all measured 378.3-378.8 us with three structurally
// different fused K-loops). Pure A/B to resolve code-caused vs environmental:
//   - 306 again  -> regression lives in the R2->R3 delta (tern path /
//                   epilogue butterfly / packed cvt); bisect next round.
//   - 378 again  -> R2's 306 was environmental; all configs equivalent.
// ---------------------------------------------------------------------------

typedef __attribute__((ext_vector_type(4))) float f32x4;
typedef __attribute__((ext_vector_type(8))) short s16x8;
typedef __attribute__((ext_vector_type(4))) short s16x4;

#define K1 784
#define K1_PAD 800          // 25 K-steps of 32
#define NHID 64
#define NOUT 10

// round-to-nearest-even f32 -> bf16 bits (finite inputs)
static __device__ __forceinline__ unsigned short f2bf_rne(float f) {
    unsigned int u = __builtin_bit_cast(unsigned int, f);
    unsigned int r = u + 0x7FFFu + ((u >> 16) & 1u);
    return (unsigned short)(r >> 16);
}

// block-wide f64 sum for 256-thread blocks (4 waves)
static __device__ double block_sum256(double v, double* red) {
    #pragma unroll
    for (int off = 32; off > 0; off >>= 1) v += __shfl_down(v, off, 64);
    const int w = threadIdx.x >> 6;
    const int lane = threadIdx.x & 63;
    __syncthreads();                 // protect red[] reuse across calls
    if (lane == 0) red[w] = v;
    __syncthreads();
    return red[0] + red[1] + red[2] + red[3];
}

// ---------------------------------------------------------------------------
// hdr layout (doubles): [0]=sumabs(W1) [1]=sumabs(W2) [2]=sm1 [3]=cn1 [4]=sm2 [5]=cn2
// ---------------------------------------------------------------------------
__global__ __launch_bounds__(256) void tern_sum_kernel(
    const float* __restrict__ W1, const float* __restrict__ W2,
    double* __restrict__ hdr)
{
    __shared__ double red[4];
    double s = 0.0;
    for (int i = blockIdx.x * 256 + threadIdx.x; i < NHID * K1; i += gridDim.x * 256)
        s += (double)fabsf(W1[i]);
    s = block_sum256(s, red);
    if (threadIdx.x == 0) atomicAdd(&hdr[0], s);

    if (blockIdx.x == 0) {
        double s2 = 0.0;
        for (int i = threadIdx.x; i < NOUT * NHID; i += 256)
            s2 += (double)fabsf(W2[i]);
        s2 = block_sum256(s2, red);
        if (threadIdx.x == 0) atomicAdd(&hdr[1], s2);
    }
}

__global__ __launch_bounds__(256) void tern_quant_kernel(
    const float* __restrict__ W1, const float* __restrict__ W2,
    unsigned short* __restrict__ W1q, unsigned short* __restrict__ W2q,
    double* __restrict__ hdr)
{
    __shared__ double red[4];
    const float delta1 = (float)(0.7 * hdr[0] / (double)(NHID * K1));

    double sm = 0.0, cn = 0.0;
    for (int i = blockIdx.x * 256 + threadIdx.x; i < NHID * K1_PAD; i += gridDim.x * 256) {
        int n = i / K1_PAD;
        int k = i - n * K1_PAD;
        unsigned short v = 0;
        if (k < K1) {
            float w = W1[n * K1 + k];
            float a = fabsf(w);
            if (a > delta1) { v = (w > 0.0f) ? 0x3F80u : 0xBF80u; sm += (double)a; cn += 1.0; }
        }
        W1q[i] = v;
    }
    sm = block_sum256(sm, red);
    cn = block_sum256(cn, red);
    if (threadIdx.x == 0) { atomicAdd(&hdr[2], sm); atomicAdd(&hdr[3], cn); }

    if (blockIdx.x == 0) {
        const float delta2 = (float)(0.7 * hdr[1] / (double)(NOUT * NHID));
        double sm2 = 0.0, cn2 = 0.0;
        for (int i = threadIdx.x; i < 16 * NHID; i += 256) {
            int n = i >> 6;
            int k = i & 63;
            unsigned short v = 0;
            if (n < NOUT) {
                float w = W2[n * NHID + k];
                float a = fabsf(w);
                if (a > delta2) { v = (w > 0.0f) ? 0x3F80u : 0xBF80u; sm2 += (double)a; cn2 += 1.0; }
            }
            W2q[i] = v;
        }
        sm2 = block_sum256(sm2, red);
        cn2 = block_sum256(cn2, red);
        if (threadIdx.x == 0) { atomicAdd(&hdr[4], sm2); atomicAdd(&hdr[5], cn2); }
    }
}

// ---------------------------------------------------------------------------
// Fused 2-layer kernel. 256 threads = 4 waves; each wave: 16 batch rows x all
// 64 hidden features, then 16x10 outputs. Grid: nrows/64.
//
// Per K-step (32 floats/row), each wave stages its 16x32 fp32 tile:
//   sweep0: lane i loads rows m0+(i>>3), 16B at float (i&7)*4   -> 8x128B txns
//   sweep1: same for rows m0+8+(i>>3)
// convert to bf16, write to wave-private LDS (contiguous, conflict-free),
// read back MFMA A-fragments (lane: row=lane&15, k=quad*8). Double-buffered;
// next chunk's global loads issue one full iteration ahead.
//
// MFMA 16x16x32 bf16 layouts (m89/m91/m120-verified):
//   A[m=lane&15][k=quad*8+j], B[n=lane&15][k=quad*8+j], C/D: col=lane&15, row=quad*4+reg
// ---------------------------------------------------------------------------
__global__ __launch_bounds__(256) void fused_kernel(
    const float* __restrict__ x,
    const float* __restrict__ b1,
    const float* __restrict__ b2,
    const short* __restrict__ W1q,   // [64][800] bf16 signs
    const short* __restrict__ W2q,   // [16][64]  bf16 signs
    const double* __restrict__ hdr,
    float* __restrict__ out)
{
    const int tid  = threadIdx.x;
    const int wave = tid >> 6;
    const int lane = tid & 63;
    const int low  = lane & 15;
    const int quad = lane >> 4;

    const int m0 = blockIdx.x * 64 + wave * 16;

    // staging-load role: 8 lanes per row, 16B per lane (contiguous 128B/row)
    const int srow = lane >> 3;      // 0..7
    const int scol = lane & 7;       // *4 floats = *16 bytes
    const float* g0 = x + (size_t)(m0 + srow) * K1 + scol * 4;
    const float* g1 = x + (size_t)(m0 + 8 + srow) * K1 + scol * 4;

    // wave-private double-buffered A-stage: [wave][buf][row 16][k 32] bf16 = 1KB/buf
    __shared__ __align__(16) unsigned short stage[4][2][16][32];
    __shared__ __align__(16) unsigned short h_lds[4][16][72];  // layer-2 A staging

    const short* wbase = W1q + (size_t)low * K1_PAD + quad * 8;

    f32x4 acc[4];
    #pragma unroll
    for (int nt = 0; nt < 4; ++nt) acc[nt] = (f32x4){0.f, 0.f, 0.f, 0.f};

    const f32x4 zero4 = (f32x4){0.f, 0.f, 0.f, 0.f};

    // prologue: load chunk 0
    f32x4 c0 = *(const f32x4*)(g0);
    f32x4 c1 = *(const f32x4*)(g1);

    int buf = 0;
    for (int ks = 0; ks < 25; ++ks) {
        // prefetch next chunk (full iteration of latency hiding)
        f32x4 n0 = zero4, n1 = zero4;
        if (ks < 24) {
            const int kf = (ks + 1) * 32 + scol * 4;
            if (kf < K1) {               // tail chunk 24: only scol<4 valid
                n0 = *(const f32x4*)(g0 + (ks + 1) * 32);
                n1 = *(const f32x4*)(g1 + (ks + 1) * 32);
            }
        }

        // convert current chunk -> bf16, stash to LDS (lane-contiguous b64s)
        s16x4 p0, p1;
        p0[0] = (short)f2bf_rne(c0[0]); p0[1] = (short)f2bf_rne(c0[1]);
        p0[2] = (short)f2bf_rne(c0[2]); p0[3] = (short)f2bf_rne(c0[3]);
        p1[0] = (short)f2bf_rne(c1[0]); p1[1] = (short)f2bf_rne(c1[1]);
        p1[2] = (short)f2bf_rne(c1[2]); p1[3] = (short)f2bf_rne(c1[3]);
        *(s16x4*)&stage[wave][buf][srow][scol * 4]     = p0;
        *(s16x4*)&stage[wave][buf][8 + srow][scol * 4] = p1;

        // wave-private LDS write->cross-lane read: drain DS pipe explicitly
        __asm__ volatile("s_waitcnt lgkmcnt(0)" ::: "memory");

        s16x8 a = *(const s16x8*)&stage[wave][buf][low][quad * 8];
        const short* wk = wbase + ks * 32;
        #pragma unroll
        for (int nt = 0; nt < 4; ++nt) {
            s16x8 b = *(const s16x8*)(wk + (size_t)nt * 16 * K1_PAD);
            acc[nt] = __builtin_amdgcn_mfma_f32_16x16x32_bf16(a, b, acc[nt], 0, 0, 0);
        }

        c0 = n0; c1 = n1; buf ^= 1;
    }

    // ---- epilogue 1: alpha1*acc + b1, relu, bf16 -> LDS (C-layout -> A-layout) ----
    const float alpha1 = (float)(hdr[2] / fmax(hdr[3], 1.0));
    const float alpha2 = (float)(hdr[4] / fmax(hdr[5], 1.0));

    #pragma unroll
    for (int nt = 0; nt < 4; ++nt) {
        const int n = nt * 16 + low;
        const float bias = b1[n];
        #pragma unroll
        for (int r = 0; r < 4; ++r) {
            float hv = fmaxf(0.0f, fmaf(alpha1, acc[nt][r], bias));
            h_lds[wave][quad * 4 + r][n] = f2bf_rne(hv);
        }
    }
    __asm__ volatile("s_waitcnt lgkmcnt(0)" ::: "memory");

    // ---- layer 2: [16x64] x [64x16] via 2 MFMA steps ----
    s16x8 a0 = *(const s16x8*)(&h_lds[wave][low][quad * 8]);
    s16x8 a1 = *(const s16x8*)(&h_lds[wave][low][32 + quad * 8]);
    s16x8 w0 = *(const s16x8*)(W2q + low * 64 + quad * 8);
    s16x8 w1 = *(const s16x8*)(W2q + low * 64 + 32 + quad * 8);

    f32x4 acc2 = (f32x4){0.f, 0.f, 0.f, 0.f};
    acc2 = __builtin_amdgcn_mfma_f32_16x16x32_bf16(a0, w0, acc2, 0, 0, 0);
    acc2 = __builtin_amdgcn_mfma_f32_16x16x32_bf16(a1, w1, acc2, 0, 0, 0);

    // ---- epilogue 2: alpha2*acc2 + b2, store fp32 ----
    if (low < NOUT) {
        const float bias2 = b2[low];
        #pragma unroll
        for (int r = 0; r < 4; ++r) {
            const int row = m0 + quad * 4 + r;
            out[(size_t)row * NOUT + low] = fmaf(alpha2, acc2[r], bias2);
        }
    }
}

// ---------------------------------------------------------------------------
extern "C" void kernel_launch(void* const* d_in, const int* in_sizes, int n_in,
                              void* d_out, int out_size, void* d_ws, size_t ws_size,
                              hipStream_t stream) {
    const float* x  = (const float*)d_in[0];
    const float* W1 = (const float*)d_in[1];
    const float* b1 = (const float*)d_in[2];
    const float* W2 = (const float*)d_in[3];
    const float* b2 = (const float*)d_in[4];
    float* out = (float*)d_out;

    const int nrows = in_sizes[0] / K1;   // 65536

    // ws layout: hdr 6 doubles (64B aligned block) | W1q [64*800] bf16 | W2q [16*64] bf16
    double* hdr = (double*)d_ws;
    unsigned short* W1q = (unsigned short*)((char*)d_ws + 64);
    unsigned short* W2q = W1q + NHID * K1_PAD;

    hipMemsetAsync(d_ws, 0, 64, stream);  // zero atomic accumulators

    tern_sum_kernel<<<64, 256, 0, stream>>>(W1, W2, hdr);
    tern_quant_kernel<<<64, 256, 0, stream>>>(W1, W2, W1q, W2q, hdr);

    const int nblocks = nrows / 64;       // 64 rows per block (16 per wave)
    fused_kernel<<<nblocks, 256, 0, stream>>>(x, b1, b2, (const short*)W1q,
                                              (const short*)W2q, hdr, out);
}